// Round 1
// baseline (303.016 us; speedup 1.0000x reference)
//
#include <hip/hip_runtime.h>
#include <stdint.h>

#define BATCH 32
#define H 512
#define W 512
#define NACC 16          // per-batch accumulator slots
#define TH 64            // output rows per distance tile
#define HALO 10          // MAX_DIST
#define RH (TH + 2*HALO) // 84 halo rows

// Accumulator layout per batch b (floats, acc[b*NACC + k]):
//  0: sum(p*g)   1: sum(p)    2: sum(g)
//  3: cnt_pe     4: cnt_pm    5: cnt_pj
//  6: cnt_ge     7: cnt_gm    8: cnt_gj
//  9: int_e     10: int_m    11: int_j
// 12: dsum_p2g  13: cnt_p2g  14: dsum_g2p  15: cnt_g2p

// ---------------------------------------------------------------------------
// Kernel A: 3x3 neighbor-sum stencil + dice sums, per-batch reductions.
// Grid: BATCH*32 blocks of 256 threads; each block = 16 rows of one image.
// ---------------------------------------------------------------------------
__global__ __launch_bounds__(256) void stencil_kernel(
    const float* __restrict__ pred, const float* __restrict__ gt,
    float* __restrict__ acc)
{
    int blk   = blockIdx.x;
    int b     = blk >> 5;          // image
    int chunk = blk & 31;          // 16-row chunk
    int y0    = chunk * 16;
    const float* pimg = pred + (size_t)b * H * W;
    const float* gimg = gt   + (size_t)b * H * W;

    float v0=0,v1=0,v2=0,v3=0,v4=0,v5=0,v6=0,v7=0,v8=0,v9=0,v10=0,v11=0;

    for (int i = threadIdx.x; i < 16 * W; i += 256) {
        int y = y0 + (i >> 9);
        int x = i & 511;
        float p = pimg[y * W + x];
        float g = gimg[y * W + x];
        v0 += p * g; v1 += p; v2 += g;

        float np = 0.f, ng = 0.f;
        #pragma unroll
        for (int dy = -1; dy <= 1; ++dy) {
            #pragma unroll
            for (int dx = -1; dx <= 1; ++dx) {
                if (dy == 0 && dx == 0) continue;
                int yy = y + dy, xx = x + dx;
                if ((unsigned)yy < (unsigned)H && (unsigned)xx < (unsigned)W) {
                    np += pimg[yy * W + xx];
                    ng += gimg[yy * W + xx];
                }
            }
        }
        bool pon = p > 0.5f, gon = g > 0.5f;
        bool pe = pon && (np == 1.f), pm = pon && (np == 2.f), pj = pon && (np > 2.f);
        bool ge = gon && (ng == 1.f), gm = gon && (ng == 2.f), gj = gon && (ng > 2.f);
        v3 += pe; v4 += pm; v5 += pj;
        v6 += ge; v7 += gm; v8 += gj;
        v9  += (pe && ge);
        v10 += (pm && gm);
        v11 += (pj && gj);
    }

    float vals[12] = {v0,v1,v2,v3,v4,v5,v6,v7,v8,v9,v10,v11};
    #pragma unroll
    for (int j = 0; j < 12; ++j)
        #pragma unroll
        for (int off = 32; off; off >>= 1)
            vals[j] += __shfl_down(vals[j], off, 64);

    __shared__ float red[4][12];
    int lane = threadIdx.x & 63, wid = threadIdx.x >> 6;
    if (lane == 0) {
        #pragma unroll
        for (int j = 0; j < 12; ++j) red[wid][j] = vals[j];
    }
    __syncthreads();
    if (threadIdx.x < 12) {
        float s = red[0][threadIdx.x] + red[1][threadIdx.x]
                + red[2][threadIdx.x] + red[3][threadIdx.x];
        atomicAdd(&acc[b * NACC + threadIdx.x], s);
    }
}

// ---------------------------------------------------------------------------
// Kernel B: clamped Chebyshev distance transform, fused both passes in LDS.
// dist(p) = min(max(d_cheb,1),10), d_cheb = Chebyshev dist to nearest ref>0.5.
// Grid: (H/TH, BATCH, 2); dir 0: ref=gt,tgt=pred (p2g); dir 1: ref=pred,tgt=gt.
// ---------------------------------------------------------------------------
__global__ __launch_bounds__(256) void dist_kernel(
    const float* __restrict__ pred, const float* __restrict__ gt,
    float* __restrict__ acc)
{
    __shared__ uint64_t bits[RH][8];     // 84 rows x 512 bits
    __shared__ uint8_t  hd[RH][W];       // horizontal chebyshev component, 0..11
    __shared__ float    red2[4][2];

    int tile = blockIdx.x;
    int b    = blockIdx.y;
    int dir  = blockIdx.z;
    const float* ref = (dir == 0 ? gt   : pred) + (size_t)b * H * W;
    const float* tgt = (dir == 0 ? pred : gt)   + (size_t)b * H * W;
    int y0 = tile * TH;

    int lane = threadIdx.x & 63, wid = threadIdx.x >> 6;

    // Phase 1: row bitmasks via ballot (wave-uniform loop => full-wave ballot)
    for (int s = wid; s < RH * 8; s += 4) {
        int r = s >> 3, seg = s & 7;
        int ry = y0 - HALO + r;
        float v = 0.f;
        if ((unsigned)ry < (unsigned)H) v = ref[ry * W + seg * 64 + lane];
        unsigned long long m = __ballot(v > 0.5f);
        if (lane == 0) bits[r][seg] = m;
    }
    __syncthreads();

    // Phase 2: horizontal distance per pixel from 21-bit window
    for (int i = threadIdx.x; i < RH * W; i += 256) {
        int r = i >> 9, x = i & 511;
        int base = x - 10;
        int q = base >> 6;                 // floor(base/64), arithmetic shift
        int off = base - (q << 6);         // 0..63
        uint64_t lo = (q >= 0 && q < 8) ? bits[r][q] : 0ULL;
        uint64_t hi = (q + 1 >= 0 && q + 1 < 8) ? bits[r][q + 1] : 0ULL;
        uint64_t w = (off ? ((lo >> off) | (hi << (64 - off))) : lo) & 0x1FFFFFULL;
        int d;
        if (w == 0) d = 11;
        else {
            int dr = 11, dl = 11;
            unsigned wr = (unsigned)(w >> 10);     // center..right (bits 10..20)
            if (wr) dr = __ffs(wr) - 1;
            unsigned wl = (unsigned)(w & 0x7FFu);  // left..center (bits 0..10)
            if (wl) dl = 10 - (31 - __clz(wl));
            d = dr < dl ? dr : dl;
        }
        hd[r][x] = (uint8_t)d;
    }
    __syncthreads();

    // Phase 3: vertical pass + target-masked accumulation
    float dsum = 0.f, dcnt = 0.f;
    for (int y = 0; y < TH; ++y) {
        int ry = y0 + y;
        for (int x = threadIdx.x; x < W; x += 256) {
            float t = tgt[ry * W + x];
            if (t > 0.5f) {
                int dmin = 11;
                #pragma unroll
                for (int k = 0; k < 21; ++k) {
                    int ad = (k < 10) ? (10 - k) : (k - 10);
                    int h = hd[y + k][x];
                    int v = ad > h ? ad : h;
                    dmin = v < dmin ? v : dmin;
                }
                float dist = (dmin >= 11) ? 10.f : (float)(dmin < 1 ? 1 : dmin);
                dsum += dist;
                dcnt += 1.f;
            }
        }
    }

    #pragma unroll
    for (int off = 32; off; off >>= 1) {
        dsum += __shfl_down(dsum, off, 64);
        dcnt += __shfl_down(dcnt, off, 64);
    }
    if (lane == 0) { red2[wid][0] = dsum; red2[wid][1] = dcnt; }
    __syncthreads();
    if (threadIdx.x == 0) {
        float s = red2[0][0] + red2[1][0] + red2[2][0] + red2[3][0];
        float c = red2[0][1] + red2[1][1] + red2[2][1] + red2[3][1];
        atomicAdd(&acc[b * NACC + 12 + dir * 2], s);
        atomicAdd(&acc[b * NACC + 13 + dir * 2], c);
    }
}

// ---------------------------------------------------------------------------
// Kernel C: combine per-batch accumulators into the final scalar.
// ---------------------------------------------------------------------------
__global__ __launch_bounds__(64) void final_kernel(
    const float* __restrict__ acc, float* __restrict__ out)
{
    int b = threadIdx.x;
    float dice = 0.f, sloss = 0.f, med = 0.f;
    if (b < BATCH) {
        const float* a = acc + b * NACC;
        float inter = a[0], ps = a[1], gs = a[2];
        dice = (2.f * inter + 1.f) / (ps + gs + 1.f);

        float pe = a[3], pm = a[4], pj = a[5];
        float ge = a[6], gm = a[7], gj = a[8];
        float ie = a[9], im = a[10], ij = a[11];
        float e_iou = (ie + 1.f) / (pe + ge - ie + 1.f);
        float m_iou = (im + 1.f) / (pm + gm - im + 1.f);
        float j_iou = (ij + 1.f) / (pj + gj - ij + 1.f);
        float total = ge + gj + gm + 1.f;
        sloss = 1.f - ((ge / total) * e_iou + (gj / total) * j_iou + (gm / total) * m_iou);

        float p2g = a[12] / (a[13] + 1.f);
        float g2p = a[14] / (a[15] + 1.f);
        med = ((p2g + g2p) * 0.5f) / 10.f;
    }
    #pragma unroll
    for (int off = 32; off; off >>= 1) {
        dice  += __shfl_down(dice,  off, 64);
        sloss += __shfl_down(sloss, off, 64);
        med   += __shfl_down(med,   off, 64);
    }
    if (threadIdx.x == 0) {
        float dice_loss  = 1.f - dice / (float)BATCH;
        float structural = sloss / (float)BATCH;
        float medial     = med / (float)BATCH;
        float avg = (dice_loss + structural + medial) / 3.f;
        float r = dice_loss  / (dice_loss  + 1.f) * avg
                + structural / (structural + 1.f) * avg
                + medial     / (medial     + 1.f) * avg;
        out[0] = r;
    }
}

extern "C" void kernel_launch(void* const* d_in, const int* in_sizes, int n_in,
                              void* d_out, int out_size, void* d_ws, size_t ws_size,
                              hipStream_t stream)
{
    const float* pred = (const float*)d_in[0];
    const float* gt   = (const float*)d_in[1];
    float* acc = (float*)d_ws;
    float* out = (float*)d_out;

    hipMemsetAsync(acc, 0, BATCH * NACC * sizeof(float), stream);
    stencil_kernel<<<dim3(BATCH * 32), 256, 0, stream>>>(pred, gt, acc);
    dist_kernel<<<dim3(H / TH, BATCH, 2), 256, 0, stream>>>(pred, gt, acc);
    final_kernel<<<1, 64, 0, stream>>>(acc, out);
}

// Round 2
// 174.783 us; speedup vs baseline: 1.7337x; 1.7337x over previous
//
#include <hip/hip_runtime.h>
#include <stdint.h>

#define BATCH 32
#define H 512
#define W 512
#define NACC 16          // per-batch accumulator slots
#define TH 32            // output rows per distance tile
#define HALO 10          // MAX_DIST
#define RH (TH + 2*HALO) // 52 rows incl. halo
#define WQ (W/4)         // 128 packed words per row

// Accumulator layout per batch b (floats, acc[b*NACC + k]):
//  0: sum(p*g)   1: sum(p)    2: sum(g)
//  3: cnt_pe     4: cnt_pm    5: cnt_pj
//  6: cnt_ge     7: cnt_gm    8: cnt_gj
//  9: int_e     10: int_m    11: int_j
// 12: dsum_p2g  13: cnt_p2g  14: dsum_g2p  15: cnt_g2p

// ---------------------------------------------------------------------------
// Kernel A: separable 3x3 neighbor-sum stencil + dice sums.
// Each thread handles one float4 quad; col-sums shared across lanes via shfl.
// Grid: BATCH*32 blocks x 256 threads; block = 16 rows of one image.
// ---------------------------------------------------------------------------
__device__ __forceinline__ void colsum_quad(
    const float* __restrict__ img, int y, int x4, int lane,
    bool has_m, bool has_p, float4& rc, float s[6])
{
    const float* rowm = img + (size_t)(y - 1) * W;
    const float* rowc = img + (size_t)y * W;
    const float* rowp = img + (size_t)(y + 1) * W;

    float4 rm = has_m ? *reinterpret_cast<const float4*>(rowm + x4)
                      : make_float4(0.f, 0.f, 0.f, 0.f);
    rc = *reinterpret_cast<const float4*>(rowc + x4);
    float4 rp = has_p ? *reinterpret_cast<const float4*>(rowp + x4)
                      : make_float4(0.f, 0.f, 0.f, 0.f);

    s[1] = rm.x + rc.x + rp.x;
    s[2] = rm.y + rc.y + rp.y;
    s[3] = rm.z + rc.z + rp.z;
    s[4] = rm.w + rc.w + rp.w;

    // left edge: lane-1's s[4]; right edge: lane+1's s[1]
    float sl = __shfl_up(s[4], 1, 64);
    float sr = __shfl_down(s[1], 1, 64);
    if (lane == 0) {
        sl = 0.f;
        if (x4 > 0) {
            float a = has_m ? rowm[x4 - 1] : 0.f;
            float c = rowc[x4 - 1];
            float d = has_p ? rowp[x4 - 1] : 0.f;
            sl = a + c + d;
        }
    }
    if (lane == 63) {
        sr = 0.f;
        if (x4 + 4 < W) {
            float a = has_m ? rowm[x4 + 4] : 0.f;
            float c = rowc[x4 + 4];
            float d = has_p ? rowp[x4 + 4] : 0.f;
            sr = a + c + d;
        }
    }
    s[0] = sl;
    s[5] = sr;
}

__global__ __launch_bounds__(256) void stencil_kernel(
    const float* __restrict__ pred, const float* __restrict__ gt,
    float* __restrict__ acc)
{
    int blk   = blockIdx.x;
    int b     = blk >> 5;
    int chunk = blk & 31;
    int y0    = chunk * 16;
    const float* pimg = pred + (size_t)b * H * W;
    const float* gimg = gt   + (size_t)b * H * W;

    int tid    = threadIdx.x;
    int lane   = tid & 63;
    int qi     = tid & 127;    // quad within row
    int rowsel = tid >> 7;     // 0/1
    int x4     = qi * 4;

    float v0=0,v1=0,v2=0,v3=0,v4=0,v5=0,v6=0,v7=0,v8=0,v9=0,v10=0,v11=0;

    for (int it = 0; it < 8; ++it) {
        int y = y0 + it * 2 + rowsel;
        bool has_m = y > 0, has_p = y < H - 1;

        float4 pc, gc;
        float ps[6], gs[6];
        colsum_quad(pimg, y, x4, lane, has_m, has_p, pc, ps);
        colsum_quad(gimg, y, x4, lane, has_m, has_p, gc, gs);

        v0 += pc.x * gc.x + pc.y * gc.y + pc.z * gc.z + pc.w * gc.w;
        v1 += pc.x + pc.y + pc.z + pc.w;
        v2 += gc.x + gc.y + gc.z + gc.w;

        float pcv[4] = {pc.x, pc.y, pc.z, pc.w};
        float gcv[4] = {gc.x, gc.y, gc.z, gc.w};
        #pragma unroll
        for (int j = 0; j < 4; ++j) {
            float np = ps[j] + ps[j+1] + ps[j+2] - pcv[j];
            float ng = gs[j] + gs[j+1] + gs[j+2] - gcv[j];
            bool pon = pcv[j] > 0.5f, gon = gcv[j] > 0.5f;
            bool pe = pon && (np == 1.f), pm = pon && (np == 2.f), pj = pon && (np > 2.f);
            bool ge = gon && (ng == 1.f), gm = gon && (ng == 2.f), gj = gon && (ng > 2.f);
            v3 += pe; v4 += pm; v5 += pj;
            v6 += ge; v7 += gm; v8 += gj;
            v9  += (pe && ge);
            v10 += (pm && gm);
            v11 += (pj && gj);
        }
    }

    float vals[12] = {v0,v1,v2,v3,v4,v5,v6,v7,v8,v9,v10,v11};
    #pragma unroll
    for (int j = 0; j < 12; ++j)
        #pragma unroll
        for (int off = 32; off; off >>= 1)
            vals[j] += __shfl_down(vals[j], off, 64);

    __shared__ float red[4][12];
    int wid = tid >> 6;
    if (lane == 0) {
        #pragma unroll
        for (int j = 0; j < 12; ++j) red[wid][j] = vals[j];
    }
    __syncthreads();
    if (tid < 12) {
        float s = red[0][tid] + red[1][tid] + red[2][tid] + red[3][tid];
        atomicAdd(&acc[b * NACC + tid], s);
    }
}

// ---------------------------------------------------------------------------
// Kernel B: clamped Chebyshev distance transform.
// hd packed 4 cols/u32; vertical pass center-outward with early exit.
// Grid: (H/TH=16, BATCH, 2); dir 0: ref=gt,tgt=pred; dir 1: ref=pred,tgt=gt.
// ---------------------------------------------------------------------------
__global__ __launch_bounds__(256) void dist_kernel(
    const float* __restrict__ pred, const float* __restrict__ gt,
    float* __restrict__ acc)
{
    __shared__ uint64_t bits[RH][8];       // row on-bitmasks
    __shared__ uint32_t hdp[RH][WQ];       // horizontal dist, 4 bytes = 4 cols
    __shared__ float    red2[4][2];

    int tile = blockIdx.x;
    int b    = blockIdx.y;
    int dir  = blockIdx.z;
    const float* ref = (dir == 0 ? gt   : pred) + (size_t)b * H * W;
    const float* tgt = (dir == 0 ? pred : gt)   + (size_t)b * H * W;
    int y0 = tile * TH;

    int tid = threadIdx.x, lane = tid & 63, wid = tid >> 6;

    // Phase 1: row bitmasks via full-wave ballot
    for (int s = wid; s < RH * 8; s += 4) {
        int r = s >> 3, seg = s & 7;
        int ry = y0 - HALO + r;
        float v = 0.f;
        if ((unsigned)ry < (unsigned)H) v = ref[ry * W + seg * 64 + lane];
        unsigned long long m = __ballot(v > 0.5f);
        if (lane == 0) bits[r][seg] = m;
    }
    __syncthreads();

    // Phase 2: horizontal distance, 4 cols per thread-iteration, packed u32
    for (int i = tid; i < RH * WQ; i += 256) {
        int r = i >> 7, xw = i & (WQ - 1);
        int base = xw * 4 - 10;
        int q    = base >> 6;                  // arithmetic floor
        int off  = base - (q << 6);            // 0..63 (never 0 here, but guarded)
        uint64_t lo = (q >= 0) ? bits[r][q] : 0ULL;
        uint64_t hi = (q + 1 <= 7) ? bits[r][q + 1] : 0ULL;
        uint64_t span = off ? ((lo >> off) | (hi << (64 - off))) : lo;
        uint32_t packed = 0;
        #pragma unroll
        for (int j = 0; j < 4; ++j) {
            uint32_t wnd = (uint32_t)((span >> j) & 0x1FFFFFULL);
            int d;
            if (!wnd) d = 11;
            else {
                int dr = 11, dl = 11;
                uint32_t wr = wnd >> 10;       // center..+10
                if (wr) dr = __ffs(wr) - 1;
                uint32_t wl = wnd & 0x7FFu;    // -10..center
                if (wl) dl = 10 - (31 - __clz(wl));
                d = dr < dl ? dr : dl;
            }
            packed |= (uint32_t)d << (8 * j);
        }
        hdp[r][xw] = packed;
    }
    __syncthreads();

    // Phase 3: vertical min of max(|dy|, hd), center-outward w/ early exit
    int xw = tid & (WQ - 1);
    int yh = tid >> 7;             // row-half select
    float dsum = 0.f, dcnt = 0.f;

    for (int yy = 0; yy < TH / 2; ++yy) {
        int y  = yh * (TH / 2) + yy;
        const float4 t = *reinterpret_cast<const float4*>(
            &tgt[(size_t)(y0 + y) * W + xw * 4]);

        uint32_t wc = hdp[y + HALO][xw];
        int d0 = (int)(wc & 0xFF), d1 = (int)((wc >> 8) & 0xFF);
        int d2 = (int)((wc >> 16) & 0xFF), d3 = (int)(wc >> 24);
        int dmax = max(max(d0, d1), max(d2, d3));

        for (int a = 1; a <= HALO; ++a) {
            if (a >= dmax) break;
            uint32_t wu = hdp[y + HALO - a][xw];
            uint32_t wd = hdp[y + HALO + a][xw];
            int h0 = min((int)(wu & 0xFF),         (int)(wd & 0xFF));
            int h1 = min((int)((wu >> 8) & 0xFF),  (int)((wd >> 8) & 0xFF));
            int h2 = min((int)((wu >> 16) & 0xFF), (int)((wd >> 16) & 0xFF));
            int h3 = min((int)(wu >> 24),          (int)(wd >> 24));
            d0 = min(d0, max(a, h0));
            d1 = min(d1, max(a, h1));
            d2 = min(d2, max(a, h2));
            d3 = min(d3, max(a, h3));
            dmax = max(max(d0, d1), max(d2, d3));
        }

        float f0 = (float)min(max(d0, 1), 10);
        float f1 = (float)min(max(d1, 1), 10);
        float f2 = (float)min(max(d2, 1), 10);
        float f3 = (float)min(max(d3, 1), 10);

        dcnt += (t.x > 0.5f) + (t.y > 0.5f) + (t.z > 0.5f) + (t.w > 0.5f);
        dsum += (t.x > 0.5f ? f0 : 0.f) + (t.y > 0.5f ? f1 : 0.f)
              + (t.z > 0.5f ? f2 : 0.f) + (t.w > 0.5f ? f3 : 0.f);
    }

    #pragma unroll
    for (int off = 32; off; off >>= 1) {
        dsum += __shfl_down(dsum, off, 64);
        dcnt += __shfl_down(dcnt, off, 64);
    }
    if (lane == 0) { red2[wid][0] = dsum; red2[wid][1] = dcnt; }
    __syncthreads();
    if (tid == 0) {
        float s = red2[0][0] + red2[1][0] + red2[2][0] + red2[3][0];
        float c = red2[0][1] + red2[1][1] + red2[2][1] + red2[3][1];
        atomicAdd(&acc[b * NACC + 12 + dir * 2], s);
        atomicAdd(&acc[b * NACC + 13 + dir * 2], c);
    }
}

// ---------------------------------------------------------------------------
// Kernel C: combine per-batch accumulators into the final scalar.
// ---------------------------------------------------------------------------
__global__ __launch_bounds__(64) void final_kernel(
    const float* __restrict__ acc, float* __restrict__ out)
{
    int b = threadIdx.x;
    float dice = 0.f, sloss = 0.f, med = 0.f;
    if (b < BATCH) {
        const float* a = acc + b * NACC;
        float inter = a[0], ps = a[1], gs = a[2];
        dice = (2.f * inter + 1.f) / (ps + gs + 1.f);

        float pe = a[3], pm = a[4], pj = a[5];
        float ge = a[6], gm = a[7], gj = a[8];
        float ie = a[9], im = a[10], ij = a[11];
        float e_iou = (ie + 1.f) / (pe + ge - ie + 1.f);
        float m_iou = (im + 1.f) / (pm + gm - im + 1.f);
        float j_iou = (ij + 1.f) / (pj + gj - ij + 1.f);
        float total = ge + gj + gm + 1.f;
        sloss = 1.f - ((ge / total) * e_iou + (gj / total) * j_iou + (gm / total) * m_iou);

        float p2g = a[12] / (a[13] + 1.f);
        float g2p = a[14] / (a[15] + 1.f);
        med = ((p2g + g2p) * 0.5f) / 10.f;
    }
    #pragma unroll
    for (int off = 32; off; off >>= 1) {
        dice  += __shfl_down(dice,  off, 64);
        sloss += __shfl_down(sloss, off, 64);
        med   += __shfl_down(med,   off, 64);
    }
    if (threadIdx.x == 0) {
        float dice_loss  = 1.f - dice / (float)BATCH;
        float structural = sloss / (float)BATCH;
        float medial     = med / (float)BATCH;
        float avg = (dice_loss + structural + medial) / 3.f;
        float r = dice_loss  / (dice_loss  + 1.f) * avg
                + structural / (structural + 1.f) * avg
                + medial     / (medial     + 1.f) * avg;
        out[0] = r;
    }
}

extern "C" void kernel_launch(void* const* d_in, const int* in_sizes, int n_in,
                              void* d_out, int out_size, void* d_ws, size_t ws_size,
                              hipStream_t stream)
{
    const float* pred = (const float*)d_in[0];
    const float* gt   = (const float*)d_in[1];
    float* acc = (float*)d_ws;
    float* out = (float*)d_out;

    hipMemsetAsync(acc, 0, BATCH * NACC * sizeof(float), stream);
    stencil_kernel<<<dim3(BATCH * 32), 256, 0, stream>>>(pred, gt, acc);
    dist_kernel<<<dim3(H / TH, BATCH, 2), 256, 0, stream>>>(pred, gt, acc);
    final_kernel<<<1, 64, 0, stream>>>(acc, out);
}

// Round 3
// 152.466 us; speedup vs baseline: 1.9874x; 1.1464x over previous
//
#include <hip/hip_runtime.h>
#include <stdint.h>

#define BATCH 32
#define H 512
#define W 512
#define NACC 16
#define TH 32              // center rows per tile
#define HALO 9             // need M_1..M_9 only
#define RH (TH + 2*HALO)   // 50 real rows
#define RHP 64             // padded task rows (512 word-tasks = 2/thread)

// acc[b*NACC + k]:
//  0: sum(p*g)  1: sum(p)  2: sum(g)
//  3: cnt_pe 4: cnt_pm 5: cnt_pj  6: cnt_ge 7: cnt_gm 8: cnt_gj
//  9: int_e 10: int_m 11: int_j
// 12: dsum_p2g 13: cnt_p2g 14: dsum_g2p 15: cnt_g2p

__global__ __launch_bounds__(256) void fused_kernel(
    const float* __restrict__ pred, const float* __restrict__ gt,
    float* __restrict__ acc)
{
    __shared__ uint64_t Mp[2][RHP][8];   // pred mask, double-buffered
    __shared__ uint64_t Mg[2][RHP][8];   // gt mask
    __shared__ float    EC[2][2][TH];    // [img][col 255|256][row] edge colsums
    __shared__ float    red[4][16];

    int tile = blockIdx.x, b = blockIdx.y;
    const float* pimg = pred + (size_t)b * H * W;
    const float* gimg = gt   + (size_t)b * H * W;
    int y0 = tile * TH;

    int tid = threadIdx.x, lane = tid & 63, wid = tid >> 6;

    // ---- Phase 1: row bitmasks via ballot, rows y0-9 .. y0+40, both images
    for (int s = wid; s < RH * 8; s += 4) {
        int r = s >> 3, seg = s & 7;
        int ry = y0 - HALO + r;
        float vp = 0.f, vg = 0.f;
        if ((unsigned)ry < (unsigned)H) {
            int idx = ry * W + seg * 64 + lane;
            vp = pimg[idx];
            vg = gimg[idx];
        }
        unsigned long long mp = __ballot(vp > 0.5f);
        unsigned long long mg = __ballot(vg > 0.5f);
        if (lane == 0) { Mp[0][r][seg] = mp; Mg[0][r][seg] = mg; }
    }
    // zero dummy rows 50..63
    for (int i = tid; i < (RHP - RH) * 8; i += 256) {
        int r = RH + (i >> 3), w = i & 7;
        Mp[0][r][w] = 0ULL; Mg[0][r][w] = 0ULL;
    }
    // edge colsums (cols 255,256) for the stencil cross-wave halo
    if (tid < 128) {
        int img = tid >> 6, c = (tid >> 5) & 1, r = tid & 31;
        int y = y0 + r, col = 255 + c;
        const float* im = img ? gimg : pimg;
        float sum = (y > 0     ? im[(size_t)(y-1)*W + col] : 0.f)
                  +              im[(size_t)y*W     + col]
                  + (y < H - 1 ? im[(size_t)(y+1)*W + col] : 0.f);
        EC[img][c][r] = sum;
    }
    __syncthreads();

    // ---- Target bits (center rows) from the initial masks, into registers
    uint64_t Tp = Mp[0][HALO + (tid >> 3)][tid & 7];
    uint64_t Tg = Mg[0][HALO + (tid >> 3)][tid & 7];
    int dcnt_p = __popcll(Tp);
    int dcnt_g = __popcll(Tg);
    int dsum_p = dcnt_p;   // a=0 baseline: every found pixel costs >= 1
    int dsum_g = dcnt_g;

    // ---- Stencil + dice over the 32 center rows (L2-hot re-read, rolling regs)
    int qi = tid & 127, h = tid >> 7, x4 = qi * 4;
    int ys = y0 + h * 16;
    float v[12];
    #pragma unroll
    for (int j = 0; j < 12; ++j) v[j] = 0.f;

    float4 pm4, pc4, gm4, gc4;
    {
        bool hm = ys > 0;
        pm4 = hm ? *(const float4*)(pimg + (size_t)(ys-1)*W + x4) : make_float4(0,0,0,0);
        gm4 = hm ? *(const float4*)(gimg + (size_t)(ys-1)*W + x4) : make_float4(0,0,0,0);
        pc4 = *(const float4*)(pimg + (size_t)ys*W + x4);
        gc4 = *(const float4*)(gimg + (size_t)ys*W + x4);
    }
    for (int r = 0; r < 16; ++r) {
        int y = ys + r;
        bool hp = y < H - 1;
        float4 pp4 = hp ? *(const float4*)(pimg + (size_t)(y+1)*W + x4) : make_float4(0,0,0,0);
        float4 gp4 = hp ? *(const float4*)(gimg + (size_t)(y+1)*W + x4) : make_float4(0,0,0,0);
        int ry = h * 16 + r;

        float ps[6], gs[6];
        ps[1] = pm4.x + pc4.x + pp4.x; ps[2] = pm4.y + pc4.y + pp4.y;
        ps[3] = pm4.z + pc4.z + pp4.z; ps[4] = pm4.w + pc4.w + pp4.w;
        gs[1] = gm4.x + gc4.x + gp4.x; gs[2] = gm4.y + gc4.y + gp4.y;
        gs[3] = gm4.z + gc4.z + gp4.z; gs[4] = gm4.w + gc4.w + gp4.w;

        float psl = __shfl_up(ps[4], 1, 64);
        float gsl = __shfl_up(gs[4], 1, 64);
        float psr = __shfl_down(ps[1], 1, 64);
        float gsr = __shfl_down(gs[1], 1, 64);
        if (lane == 0) {
            psl = (qi == 0) ? 0.f : EC[0][0][ry];
            gsl = (qi == 0) ? 0.f : EC[1][0][ry];
        }
        if (lane == 63) {
            psr = (qi == 127) ? 0.f : EC[0][1][ry];
            gsr = (qi == 127) ? 0.f : EC[1][1][ry];
        }
        ps[0] = psl; ps[5] = psr; gs[0] = gsl; gs[5] = gsr;

        float pcv[4] = {pc4.x, pc4.y, pc4.z, pc4.w};
        float gcv[4] = {gc4.x, gc4.y, gc4.z, gc4.w};
        v[0] += pcv[0]*gcv[0] + pcv[1]*gcv[1] + pcv[2]*gcv[2] + pcv[3]*gcv[3];
        v[1] += pcv[0] + pcv[1] + pcv[2] + pcv[3];
        v[2] += gcv[0] + gcv[1] + gcv[2] + gcv[3];
        #pragma unroll
        for (int j = 0; j < 4; ++j) {
            float np = ps[j] + ps[j+1] + ps[j+2] - pcv[j];
            float ng = gs[j] + gs[j+1] + gs[j+2] - gcv[j];
            bool pon = pcv[j] > 0.5f, gon = gcv[j] > 0.5f;
            bool pe = pon && (np == 1.f), pmb = pon && (np == 2.f), pjb = pon && (np > 2.f);
            bool ge = gon && (ng == 1.f), gmb = gon && (ng == 2.f), gjb = gon && (ng > 2.f);
            v[3] += pe;  v[4] += pmb;  v[5] += pjb;
            v[6] += ge;  v[7] += gmb;  v[8] += gjb;
            v[9]  += (pe && ge);
            v[10] += (pmb && gmb);
            v[11] += (pjb && gjb);
        }
        pm4 = pc4; pc4 = pp4; gm4 = gc4; gc4 = gp4;
    }

    // ---- 9 binary dilation steps on both masks; popcount after each
    int cur = 0;
    for (int a = 1; a <= 9; ++a) {
        #pragma unroll
        for (int k = 0; k < 2; ++k) {
            int i = tid + 256 * k;
            int r = i >> 3, w = i & 7;
            uint64_t up, md, dn;
            up = (r > 0)       ? Mp[cur][r-1][w] : 0ULL;
            md =                 Mp[cur][r][w];
            dn = (r < RHP - 1) ? Mp[cur][r+1][w] : 0ULL;
            uint64_t Xp = up | md | dn;
            up = (r > 0)       ? Mg[cur][r-1][w] : 0ULL;
            md =                 Mg[cur][r][w];
            dn = (r < RHP - 1) ? Mg[cur][r+1][w] : 0ULL;
            uint64_t Xg = up | md | dn;

            uint32_t lmp = __shfl_up  ((uint32_t)(Xp >> 63), 1, 64);
            uint32_t rlp = __shfl_down((uint32_t)(Xp & 1ULL), 1, 64);
            uint32_t lmg = __shfl_up  ((uint32_t)(Xg >> 63), 1, 64);
            uint32_t rlg = __shfl_down((uint32_t)(Xg & 1ULL), 1, 64);

            uint64_t Yp = Xp | (Xp << 1) | (Xp >> 1);
            uint64_t Yg = Xg | (Xg << 1) | (Xg >> 1);
            if (w > 0) { Yp |= (uint64_t)(lmp & 1u); Yg |= (uint64_t)(lmg & 1u); }
            if (w < 7) { Yp |= ((uint64_t)(rlp & 1u)) << 63; Yg |= ((uint64_t)(rlg & 1u)) << 63; }
            Mp[cur ^ 1][r][w] = Yp;
            Mg[cur ^ 1][r][w] = Yg;
        }
        __syncthreads();
        cur ^= 1;
        uint64_t cgv = Mg[cur][HALO + (tid >> 3)][tid & 7];
        uint64_t cpv = Mp[cur][HALO + (tid >> 3)][tid & 7];
        dsum_p += __popcll(Tp & ~cgv);   // pred targets vs gt coverage
        dsum_g += __popcll(Tg & ~cpv);   // gt targets vs pred coverage
    }

    // ---- Reductions
    #pragma unroll
    for (int j = 0; j < 12; ++j)
        #pragma unroll
        for (int off = 32; off; off >>= 1)
            v[j] += __shfl_down(v[j], off, 64);
    float dp = (float)dsum_p, cpn = (float)dcnt_p;
    float dg = (float)dsum_g, cgn = (float)dcnt_g;
    #pragma unroll
    for (int off = 32; off; off >>= 1) {
        dp  += __shfl_down(dp,  off, 64);
        cpn += __shfl_down(cpn, off, 64);
        dg  += __shfl_down(dg,  off, 64);
        cgn += __shfl_down(cgn, off, 64);
    }
    if (lane == 0) {
        #pragma unroll
        for (int j = 0; j < 12; ++j) red[wid][j] = v[j];
        red[wid][12] = dp; red[wid][13] = cpn;
        red[wid][14] = dg; red[wid][15] = cgn;
    }
    __syncthreads();
    if (tid < 16) {
        float s = red[0][tid] + red[1][tid] + red[2][tid] + red[3][tid];
        atomicAdd(&acc[b * NACC + tid], s);
    }
}

// ---------------------------------------------------------------------------
__global__ __launch_bounds__(64) void final_kernel(
    const float* __restrict__ acc, float* __restrict__ out)
{
    int b = threadIdx.x;
    float dice = 0.f, sloss = 0.f, med = 0.f;
    if (b < BATCH) {
        const float* a = acc + b * NACC;
        float inter = a[0], ps = a[1], gs = a[2];
        dice = (2.f * inter + 1.f) / (ps + gs + 1.f);

        float pe = a[3], pm = a[4], pj = a[5];
        float ge = a[6], gm = a[7], gj = a[8];
        float ie = a[9], im = a[10], ij = a[11];
        float e_iou = (ie + 1.f) / (pe + ge - ie + 1.f);
        float m_iou = (im + 1.f) / (pm + gm - im + 1.f);
        float j_iou = (ij + 1.f) / (pj + gj - ij + 1.f);
        float total = ge + gj + gm + 1.f;
        sloss = 1.f - ((ge / total) * e_iou + (gj / total) * j_iou + (gm / total) * m_iou);

        float p2g = a[12] / (a[13] + 1.f);
        float g2p = a[14] / (a[15] + 1.f);
        med = ((p2g + g2p) * 0.5f) / 10.f;
    }
    #pragma unroll
    for (int off = 32; off; off >>= 1) {
        dice  += __shfl_down(dice,  off, 64);
        sloss += __shfl_down(sloss, off, 64);
        med   += __shfl_down(med,   off, 64);
    }
    if (threadIdx.x == 0) {
        float dice_loss  = 1.f - dice / (float)BATCH;
        float structural = sloss / (float)BATCH;
        float medial     = med / (float)BATCH;
        float avg = (dice_loss + structural + medial) / 3.f;
        float r = dice_loss  / (dice_loss  + 1.f) * avg
                + structural / (structural + 1.f) * avg
                + medial     / (medial     + 1.f) * avg;
        out[0] = r;
    }
}

extern "C" void kernel_launch(void* const* d_in, const int* in_sizes, int n_in,
                              void* d_out, int out_size, void* d_ws, size_t ws_size,
                              hipStream_t stream)
{
    const float* pred = (const float*)d_in[0];
    const float* gt   = (const float*)d_in[1];
    float* acc = (float*)d_ws;
    float* out = (float*)d_out;

    hipMemsetAsync(acc, 0, BATCH * NACC * sizeof(float), stream);
    fused_kernel<<<dim3(H / TH, BATCH), 256, 0, stream>>>(pred, gt, acc);
    final_kernel<<<1, 64, 0, stream>>>(acc, out);
}

// Round 4
// 133.513 us; speedup vs baseline: 2.2696x; 1.1420x over previous
//
#include <hip/hip_runtime.h>
#include <stdint.h>

#define BATCH 32
#define H 512
#define W 512
#define NACC 16
#define TH 32              // center rows per tile
#define HALO 9             // need M_1..M_9 only
#define RH (TH + 2*HALO)   // 50 real rows
#define RHP 64             // padded rows: 512 word-tasks = 1/thread
#define NT 512
#define NW (NT/64)         // 8 waves

// acc[b*NACC + k]:
//  0: sum(p*g)  1: sum(p)  2: sum(g)
//  3: cnt_pe 4: cnt_pm 5: cnt_pj  6: cnt_ge 7: cnt_gm 8: cnt_gj
//  9: int_e 10: int_m 11: int_j
// 12: dsum_p2g 13: cnt_p2g 14: dsum_g2p 15: cnt_g2p

__global__ __launch_bounds__(NT, 4) void fused_kernel(
    const float* __restrict__ pred, const float* __restrict__ gt,
    float* __restrict__ acc)
{
    __shared__ uint64_t Mp[2][RHP][8];   // pred mask, double-buffered
    __shared__ uint64_t Mg[2][RHP][8];   // gt mask
    __shared__ float    EC[2][TH];       // pred colsums at cols 255|256
    __shared__ float    red[NW][16];

    int tile = blockIdx.x, b = blockIdx.y;
    const float* pimg = pred + (size_t)b * H * W;
    const float* gimg = gt   + (size_t)b * H * W;
    int y0 = tile * TH;
    int tid = threadIdx.x, lane = tid & 63, wid = tid >> 6;

    float v0 = 0.f, v1 = 0.f;   // sum(p*g), sum(p) — folded into phase 1

    // ---- Phase 1: ballot masks for both images, rows y0-9 .. y0+40 (x2 unrolled)
    // RH*8 = 400 tasks, stride 16 from wid<8: both s and s+8 always < 400.
    for (int s = wid; s < RH * 8; s += 2 * NW) {
        int rA = s >> 3, segA = s & 7;
        int rB = (s + NW) >> 3, segB = (s + NW) & 7;
        int ryA = y0 - HALO + rA, ryB = y0 - HALO + rB;
        float vpA = 0.f, vgA = 0.f, vpB = 0.f, vgB = 0.f;
        if ((unsigned)ryA < (unsigned)H) {
            int idx = ryA * W + segA * 64 + lane;
            vpA = pimg[idx]; vgA = gimg[idx];
        }
        if ((unsigned)ryB < (unsigned)H) {
            int idx = ryB * W + segB * 64 + lane;
            vpB = pimg[idx]; vgB = gimg[idx];
        }
        unsigned long long mpA = __ballot(vpA > 0.5f);
        unsigned long long mgA = __ballot(vgA > 0.5f);
        unsigned long long mpB = __ballot(vpB > 0.5f);
        unsigned long long mgB = __ballot(vgB > 0.5f);
        if (lane == 0) {
            Mp[0][rA][segA] = mpA; Mg[0][rA][segA] = mgA;
            Mp[0][rB][segB] = mpB; Mg[0][rB][segB] = mgB;
        }
        if (rA >= HALO && rA < HALO + TH) { v1 += vpA; v0 += (vgA > 0.5f) ? vpA : 0.f; }
        if (rB >= HALO && rB < HALO + TH) { v1 += vpB; v0 += (vgB > 0.5f) ? vpB : 0.f; }
    }
    // zero dummy rows 50..63 (14 rows x 8 words)
    if (tid < (RHP - RH) * 8) {
        int r = RH + (tid >> 3), w = tid & 7;
        Mp[0][r][w] = 0ULL; Mg[0][r][w] = 0ULL;
    }
    // pred edge colsums (cols 255,256) for the cross-wave stencil halo
    if (tid < 64) {
        int c = tid >> 5, r = tid & 31;
        int y = y0 + r, col = 255 + c;
        float sum = (y > 0     ? pimg[(size_t)(y - 1) * W + col] : 0.f)
                  +              pimg[(size_t)y * W + col]
                  + (y < H - 1 ? pimg[(size_t)(y + 1) * W + col] : 0.f);
        EC[c][r] = sum;
    }
    __syncthreads();

    // ---- Target bits for distance (center 32 rows = 256 words, tid<256)
    uint64_t Tp = 0ULL, Tg = 0ULL;
    if (tid < 256) {
        int r = HALO + (tid >> 3), w = tid & 7;
        Tp = Mp[0][r][w]; Tg = Mg[0][r][w];
    }
    int dcnt_p = __popcll(Tp), dcnt_g = __popcll(Tg);
    int dsum_p = dcnt_p, dsum_g = dcnt_g;   // a=0 baseline (dist >= 1)

    // ---- Stencil: pred via floats (rolling rows), gt via bit popcounts
    float c3=0,c4=0,c5=0,c6=0,c7=0,c8=0,c9=0,c10=0,c11=0;
    {
        int qi = tid & 127, h = tid >> 7;     // h in 0..3, 8 rows each
        int x4 = qi * 4;
        int wdx = qi >> 4;                    // word for this quad
        int ss = (qi & 15) * 4;               // bit offset of x4 in word
        int ys = y0 + h * 8;

        auto win6 = [&](int rb) -> uint32_t {
            const uint64_t* row = Mg[0][rb];
            uint64_t bm = row[wdx];
            if (ss == 0) {
                uint64_t lo = wdx ? row[wdx - 1] : 0ULL;
                return (uint32_t)(((bm << 1) | (lo >> 63)) & 0x3FULL);
            }
            uint32_t v = (uint32_t)((bm >> (ss - 1)) & 0x3FULL);
            if (ss == 60) {
                uint64_t hi = (wdx < 7) ? row[wdx + 1] : 0ULL;
                v |= ((uint32_t)hi & 1u) << 5;
            }
            return v;
        };

        int rb0 = h * 8 + 8;                  // bit-row of (ys-1)
        uint32_t wU = win6(rb0), wM = win6(rb0 + 1);

        float4 pm4, pc4;
        {
            bool hm = ys > 0;
            pm4 = hm ? *(const float4*)(pimg + (size_t)(ys - 1) * W + x4)
                     : make_float4(0, 0, 0, 0);
            pc4 = *(const float4*)(pimg + (size_t)ys * W + x4);
        }
        for (int r = 0; r < 8; ++r) {
            int y = ys + r;
            float4 pp4 = (y < H - 1) ? *(const float4*)(pimg + (size_t)(y + 1) * W + x4)
                                     : make_float4(0, 0, 0, 0);
            uint32_t wD = win6(rb0 + 2 + r);
            int ry = h * 8 + r;

            float ps[6];
            ps[1] = pm4.x + pc4.x + pp4.x; ps[2] = pm4.y + pc4.y + pp4.y;
            ps[3] = pm4.z + pc4.z + pp4.z; ps[4] = pm4.w + pc4.w + pp4.w;
            float psl = __shfl_up(ps[4], 1, 64);
            float psr = __shfl_down(ps[1], 1, 64);
            if (lane == 0)  psl = (qi == 0)   ? 0.f : EC[0][ry];
            if (lane == 63) psr = (qi == 127) ? 0.f : EC[1][ry];
            ps[0] = psl; ps[5] = psr;

            float pcv[4] = {pc4.x, pc4.y, pc4.z, pc4.w};
            #pragma unroll
            for (int j = 0; j < 4; ++j) {
                float np = ps[j] + ps[j + 1] + ps[j + 2] - pcv[j];
                bool pon = pcv[j] > 0.5f;
                bool pe  = pon && (np == 1.f);
                bool pmb = pon && (np == 2.f);
                bool pjb = pon && (np > 2.f);
                uint32_t n9 = ((wU >> j) & 7u) | (((wM >> j) & 7u) << 3) | (((wD >> j) & 7u) << 6);
                uint32_t cen = (wM >> (j + 1)) & 1u;
                int ng = __popc(n9) - (int)cen;
                bool gon = cen != 0u;
                bool ge  = gon && (ng == 1);
                bool gmb = gon && (ng == 2);
                bool gjb = gon && (ng > 2);
                c3 += pe;  c4 += pmb;  c5 += pjb;
                c6 += ge;  c7 += gmb;  c8 += gjb;
                c9  += (pe && ge);
                c10 += (pmb && gmb);
                c11 += (pjb && gjb);
            }
            pm4 = pc4; pc4 = pp4; wU = wM; wM = wD;
        }
    }

    // ---- 9 bit-dilation steps, 1 word-task/thread; popcount after each
    int cur = 0;
    int rr = tid >> 3, ww = tid & 7;
    int rc = HALO + (tid >> 3), wc = tid & 7;   // center word (valid for tid<256)
    for (int a = 1; a <= 9; ++a) {
        uint64_t up, md, dn;
        up = rr ? Mp[cur][rr - 1][ww] : 0ULL;
        md = Mp[cur][rr][ww];
        dn = (rr < RHP - 1) ? Mp[cur][rr + 1][ww] : 0ULL;
        uint64_t Xp = up | md | dn;
        up = rr ? Mg[cur][rr - 1][ww] : 0ULL;
        md = Mg[cur][rr][ww];
        dn = (rr < RHP - 1) ? Mg[cur][rr + 1][ww] : 0ULL;
        uint64_t Xg = up | md | dn;

        uint32_t lmp = __shfl_up  ((uint32_t)(Xp >> 63), 1, 64);
        uint32_t rlp = __shfl_down((uint32_t)(Xp & 1ULL), 1, 64);
        uint32_t lmg = __shfl_up  ((uint32_t)(Xg >> 63), 1, 64);
        uint32_t rlg = __shfl_down((uint32_t)(Xg & 1ULL), 1, 64);

        uint64_t Yp = Xp | (Xp << 1) | (Xp >> 1);
        uint64_t Yg = Xg | (Xg << 1) | (Xg >> 1);
        if (ww > 0) { Yp |= (uint64_t)(lmp & 1u); Yg |= (uint64_t)(lmg & 1u); }
        if (ww < 7) { Yp |= ((uint64_t)(rlp & 1u)) << 63; Yg |= ((uint64_t)(rlg & 1u)) << 63; }
        Mp[cur ^ 1][rr][ww] = Yp;
        Mg[cur ^ 1][rr][ww] = Yg;
        __syncthreads();
        cur ^= 1;
        if (tid < 256) {
            dsum_p += __popcll(Tp & ~Mg[cur][rc][wc]);  // pred targets vs gt coverage
            dsum_g += __popcll(Tg & ~Mp[cur][rc][wc]);  // gt targets vs pred coverage
        }
    }

    // ---- Reductions
    float vals[16];
    vals[0] = v0; vals[1] = v1; vals[2] = (float)dcnt_g;
    vals[3] = c3; vals[4] = c4; vals[5] = c5;
    vals[6] = c6; vals[7] = c7; vals[8] = c8;
    vals[9] = c9; vals[10] = c10; vals[11] = c11;
    vals[12] = (float)dsum_p; vals[13] = (float)dcnt_p;
    vals[14] = (float)dsum_g; vals[15] = (float)dcnt_g;
    #pragma unroll
    for (int j = 0; j < 16; ++j)
        #pragma unroll
        for (int off = 32; off; off >>= 1)
            vals[j] += __shfl_down(vals[j], off, 64);
    if (lane == 0) {
        #pragma unroll
        for (int j = 0; j < 16; ++j) red[wid][j] = vals[j];
    }
    __syncthreads();
    if (tid < 16) {
        float s = 0.f;
        #pragma unroll
        for (int wv = 0; wv < NW; ++wv) s += red[wv][tid];
        atomicAdd(&acc[b * NACC + tid], s);
    }
}

// ---------------------------------------------------------------------------
__global__ __launch_bounds__(64) void final_kernel(
    const float* __restrict__ acc, float* __restrict__ out)
{
    int b = threadIdx.x;
    float dice = 0.f, sloss = 0.f, med = 0.f;
    if (b < BATCH) {
        const float* a = acc + b * NACC;
        float inter = a[0], ps = a[1], gs = a[2];
        dice = (2.f * inter + 1.f) / (ps + gs + 1.f);

        float pe = a[3], pm = a[4], pj = a[5];
        float ge = a[6], gm = a[7], gj = a[8];
        float ie = a[9], im = a[10], ij = a[11];
        float e_iou = (ie + 1.f) / (pe + ge - ie + 1.f);
        float m_iou = (im + 1.f) / (pm + gm - im + 1.f);
        float j_iou = (ij + 1.f) / (pj + gj - ij + 1.f);
        float total = ge + gj + gm + 1.f;
        sloss = 1.f - ((ge / total) * e_iou + (gj / total) * j_iou + (gm / total) * m_iou);

        float p2g = a[12] / (a[13] + 1.f);
        float g2p = a[14] / (a[15] + 1.f);
        med = ((p2g + g2p) * 0.5f) / 10.f;
    }
    #pragma unroll
    for (int off = 32; off; off >>= 1) {
        dice  += __shfl_down(dice,  off, 64);
        sloss += __shfl_down(sloss, off, 64);
        med   += __shfl_down(med,   off, 64);
    }
    if (threadIdx.x == 0) {
        float dice_loss  = 1.f - dice / (float)BATCH;
        float structural = sloss / (float)BATCH;
        float medial     = med / (float)BATCH;
        float avg = (dice_loss + structural + medial) / 3.f;
        float r = dice_loss  / (dice_loss  + 1.f) * avg
                + structural / (structural + 1.f) * avg
                + medial     / (medial     + 1.f) * avg;
        out[0] = r;
    }
}

extern "C" void kernel_launch(void* const* d_in, const int* in_sizes, int n_in,
                              void* d_out, int out_size, void* d_ws, size_t ws_size,
                              hipStream_t stream)
{
    const float* pred = (const float*)d_in[0];
    const float* gt   = (const float*)d_in[1];
    float* acc = (float*)d_ws;
    float* out = (float*)d_out;

    hipMemsetAsync(acc, 0, BATCH * NACC * sizeof(float), stream);
    fused_kernel<<<dim3(H / TH, BATCH), NT, 0, stream>>>(pred, gt, acc);
    final_kernel<<<1, 64, 0, stream>>>(acc, out);
}